// Round 3
// baseline (131.190 us; speedup 1.0000x reference)
//
#include <hip/hip_runtime.h>
#include <math.h>

// Problem constants (from setup_inputs): x[B,D] fp32, K=8 bins per column.
#define DD   256
#define KK   8
#define DTILE 128     // d-columns per block (2 per lane, float2-vectorized)
#define ROWS  128     // b-rows per block (32 per wave)

typedef float f32x2 __attribute__((ext_vector_type(2)));  // native clang vector
// (HIP's float2 is a class type that __builtin_nontemporal_* rejects.)

// ---------------------------------------------------------------------------
// Setup kernel (UNCHANGED, harness-verified): 8 lanes per column d.
// Width-8 shfl_xor softmax max/sum, width-8 shfl_up scan for knot cumsum,
// lane k emits bin k's two Mobius coefficient quads, composed in double.
// parG: float4[D*16]; bndG: float[D*15] interior boundaries s[1..15].
// ---------------------------------------------------------------------------
__global__ __launch_bounds__(256)
void spline_setup(const float* __restrict__ uw, const float* __restrict__ uh,
                  const float* __restrict__ ud, const float* __restrict__ ul,
                  float4* __restrict__ parG, float* __restrict__ bndG) {
    const int t = blockIdx.x * blockDim.x + threadIdx.x;   // 0..2047
    const int d = t >> 3;
    const int k = t & 7;
    if (d >= DD) return;

    const float uwv = uw[d * KK + k];
    const float uhv = uh[d * KK + k];
    const float ulv = ul[d * KK + k];

    float mw = uwv, mh = uhv;
    for (int off = 1; off < 8; off <<= 1) {
        mw = fmaxf(mw, __shfl_xor(mw, off, 8));
        mh = fmaxf(mh, __shfl_xor(mh, off, 8));
    }
    const float ew = expf(uwv - mw), eh = expf(uhv - mh);
    double sw = (double)ew, sh = (double)eh;
    for (int off = 1; off < 8; off <<= 1) {
        sw += __shfl_xor(sw, off, 8);
        sh += __shfl_xor(sh, off, 8);
    }
    const double wk = 1e-3 + (1.0 - 1e-3 * KK) * ((double)ew / sw);
    const double hk = 1e-3 + (1.0 - 1e-3 * KK) * ((double)eh / sh);

    double cw = wk, ch = hk;
    for (int off = 1; off < 8; off <<= 1) {
        const double aw = __shfl_up(cw, (unsigned)off, 8);
        const double ah = __shfl_up(ch, (unsigned)off, 8);
        if (k >= off) { cw += aw; ch += ah; }
    }

    const double kxlo = (k == 0) ? -3.0 : 6.0 * (cw - wk) - 3.0;
    const double kxhi = (k == 7) ?  3.0 : 6.0 * cw - 3.0;
    const double kylo = (k == 0) ? -3.0 : 6.0 * (ch - hk) - 3.0;
    const double kyhi = (k == 7) ?  3.0 : 6.0 * ch - 3.0;

    const double d0 = (k == 0) ? (1.0 - 1e-3)
                               : (1e-3 + (double)log1pf(expf(ud[d * (KK - 1) + k - 1])));
    const double d1 = (k == 7) ? (1.0 - 1e-3)
                               : (1e-3 + (double)log1pf(expf(ud[d * (KK - 1) + k])));
    const double l = 0.025 + 0.95 * (1.0 / (1.0 + (double)expf(-ulv)));

    const double wdt = kxhi - kxlo;
    const double hgt = kyhi - kylo;
    const double delta = hgt / wdt;
    const double wb = sqrt(d0 / d1);                       // wa = 1
    const double wc = (l * d0 + (1.0 - l) * wb * d1) / delta;
    const double ya = kylo, yb = kyhi;
    const double wcyc = wc * (((1.0 - l) * ya + l * wb * yb) / ((1.0 - l) + l * wb));
    const double wbyb = wb * yb;
    const double invw = 1.0 / wdt, icw = kxlo;

    {
        const double A = ya * l, P = wcyc - ya, C = l, Q = wc - 1.0;
        const double Bp = P * invw, Dp = Q * invw;
        parG[d * 16 + 2 * k] = make_float4((float)(A - Bp * icw), (float)Bp,
                                           (float)(C - Dp * icw), (float)Dp);
    }
    {
        const double A = wcyc - wbyb * l, P = wbyb - wcyc, C = wc - wb * l, Q = wb - wc;
        const double Bp = P * invw, Dp = Q * invw;
        parG[d * 16 + 2 * k + 1] = make_float4((float)(A - Bp * icw), (float)Bp,
                                               (float)(C - Dp * icw), (float)Dp);
    }
    if (k > 0) bndG[d * 15 + (2 * k - 1)] = (float)kxlo;
    bndG[d * 15 + (2 * k)] = (float)(kxlo + l * wdt);
}

// ---------------------------------------------------------------------------
// Per-element evaluator (math identical to verified version): branchless
// 4-level binary search over 15 register-resident boundaries, one rotated
// LDS float4 fetch, Mobius evaluate, identity outside [-3,3].
// ---------------------------------------------------------------------------
__device__ __forceinline__ float spline_eval(
    float xo,
    float b1, float b2, float b3, float b4, float b5, float b6, float b7, float b8,
    float b9, float b10, float b11, float b12, float b13, float b14, float b15,
    const float4* __restrict__ sp, int pbase, int rot) {
    const float xc = __builtin_amdgcn_fmed3f(xo, -3.0f, 3.0f);
    const bool c3 = xc >= b8;
    const float m2 = c3 ? b12 : b4;
    const bool c2 = xc >= m2;
    const float m1 = c3 ? (c2 ? b14 : b10) : (c2 ? b6 : b2);
    const bool c1 = xc >= m1;
    const float t01 = c1 ? b3  : b1;
    const float t23 = c1 ? b7  : b5;
    const float t45 = c1 ? b11 : b9;
    const float t67 = c1 ? b15 : b13;
    const float m0 = c3 ? (c2 ? t67 : t45) : (c2 ? t23 : t01);
    const bool c0 = xc >= m0;
    const int j = (c3 ? 8 : 0) + (c2 ? 4 : 0) + (c1 ? 2 : 0) + (c0 ? 1 : 0);

    const float4 p = sp[pbase + ((j + rot) & 15)];
    const float num = fmaf(p.y, xc, p.x);
    const float den = fmaf(p.w, xc, p.z);
    const float res = __fdividef(num, den);
    return (xo == xc) ? res : xo;   // outside [-3,3] (and NaN) -> identity
}

// ---------------------------------------------------------------------------
// Main kernel v4: float2-vectorized (R2, verified) + distance-2 ping-pong
// software pipeline. R2's loop ended each iteration with cur[r]=nxt[r],
// which forces a full vmcnt(0) drain of loads issued ~200 cycles earlier --
// bursty issue, only 4 loads in flight. v4 keeps two named quads qA/qB
// (static indexing only): wait on qA (vmcnt(4): qB's loads stay in flight),
// snapshot to temps, immediately re-issue qA's next 4 loads, then compute.
// Steady state: 8 nontemporal loads (4 KB/wave, 64 KB/CU) outstanding,
// no full drains. x is read-once -> nontemporal loads skip cache pollution.
//
// LDS layout/bank math unchanged from verified R2 version: [sub][grp][slot]
// stride-17 float4, bank = 4*(grp+slot) mod 32, rot = lane>>3 spreads the
// 8-lane alias classes. LDS 34816 B -> 4 blocks/CU; (256,4) caps VGPR at
// 128 (est ~90: 30 bnd + 24 pipeline + temps; no spills).
// Grid = (2, 512) = 1024 blocks = exactly 4/CU: one residency wave, no tail.
// ---------------------------------------------------------------------------
__global__ __launch_bounds__(256, 4)
void spline_main(const float* __restrict__ x, const float4* __restrict__ parG,
                 const float* __restrict__ bndG, float* __restrict__ out, int B) {
    __shared__ float4 s_par[2 * 64 * 17];   // 34816 B

    const int tid = threadIdx.x;
    const int dbase = blockIdx.x * DTILE;
    const int lane = tid & 63;
    const int w    = tid >> 6;
    const int d0   = dbase + lane * 2;

    const size_t rowbase = (size_t)(blockIdx.y * ROWS + w * 32) * DD + d0;
    const f32x2* __restrict__ xp = (const f32x2*)(x + rowbase);
    f32x2*       __restrict__ op = (f32x2*)(out + rowbase);
    const int RS = DD / 2;   // row stride in f32x2 units = 128

    // prologue: 8 loads in flight before anything else (overlaps staging)
    f32x2 qA[4], qB[4];
#pragma unroll
    for (int r = 0; r < 4; ++r)
        qA[r] = __builtin_nontemporal_load(&xp[(size_t)r * RS]);
#pragma unroll
    for (int r = 0; r < 4; ++r)
        qB[r] = __builtin_nontemporal_load(&xp[(size_t)(4 + r) * RS]);

    // boundary loads for both owned columns (independent of LDS staging)
    const float* bpa = bndG + (size_t)d0 * 15;
    const float* bpb = bpa + 15;
    const float a1 = bpa[0],  a2 = bpa[1],  a3 = bpa[2],  a4 = bpa[3];
    const float a5 = bpa[4],  a6 = bpa[5],  a7 = bpa[6],  a8 = bpa[7];
    const float a9 = bpa[8],  a10 = bpa[9], a11 = bpa[10], a12 = bpa[11];
    const float a13 = bpa[12], a14 = bpa[13], a15 = bpa[14];
    const float c1 = bpb[0],  c2 = bpb[1],  c3 = bpb[2],  c4 = bpb[3];
    const float c5 = bpb[4],  c6 = bpb[5],  c7 = bpb[6],  c8 = bpb[7];
    const float c9 = bpb[8],  c10 = bpb[9], c11 = bpb[10], c12 = bpb[11];
    const float c13 = bpb[12], c14 = bpb[13], c15 = bpb[14];

    // stage par for the block's 128 columns; column c -> [c&1][c>>1][slot]
    for (int i = tid; i < DTILE * 16; i += 256) {
        const int col = i >> 4, v = i & 15;
        const int grp = col >> 1, sub = col & 1;
        s_par[(sub * 64 + grp) * 17 + ((v + (grp >> 3)) & 15)] =
            parG[(size_t)(dbase + col) * 16 + v];
    }
    __syncthreads();

    const int pb0 = lane * 17;           // sub=0 (even column d0)
    const int pb1 = (64 + lane) * 17;    // sub=1 (odd column d0+1)
    const int rot = lane >> 3;

    // process quad t[0..3] holding rows q*4 .. q*4+3
#define PROCESS_QUAD(tq, q)                                                     \
    _Pragma("unroll")                                                           \
    for (int r = 0; r < 4; ++r) {                                               \
        const f32x2 v = (tq)[r];                                                \
        f32x2 o;                                                                \
        o.x = spline_eval(v.x, a1, a2, a3, a4, a5, a6, a7, a8,                  \
                          a9, a10, a11, a12, a13, a14, a15, s_par, pb0, rot);   \
        o.y = spline_eval(v.y, c1, c2, c3, c4, c5, c6, c7, c8,                  \
                          c9, c10, c11, c12, c13, c14, c15, s_par, pb1, rot);   \
        __builtin_nontemporal_store(o, &op[(size_t)((q) * 4 + r) * RS]);        \
    }

#pragma unroll 1
    for (int gp = 0; gp < 4; ++gp) {     // 4 pairs of quads = 8 quads = 32 rows
        {   // quad 2*gp lives in qA; its replacement is quad 2*gp+2
            f32x2 t[4];
#pragma unroll
            for (int r = 0; r < 4; ++r) t[r] = qA[r];   // waits vmcnt(4) only
            if (gp < 3) {
#pragma unroll
                for (int r = 0; r < 4; ++r)
                    qA[r] = __builtin_nontemporal_load(
                        &xp[(size_t)((2 * gp + 2) * 4 + r) * RS]);
            }
            PROCESS_QUAD(t, 2 * gp)
        }
        {   // quad 2*gp+1 lives in qB; its replacement is quad 2*gp+3
            f32x2 t[4];
#pragma unroll
            for (int r = 0; r < 4; ++r) t[r] = qB[r];
            if (gp < 3) {
#pragma unroll
                for (int r = 0; r < 4; ++r)
                    qB[r] = __builtin_nontemporal_load(
                        &xp[(size_t)((2 * gp + 3) * 4 + r) * RS]);
            }
            PROCESS_QUAD(t, 2 * gp + 1)
        }
    }
#undef PROCESS_QUAD
}

extern "C" void kernel_launch(void* const* d_in, const int* in_sizes, int n_in,
                              void* d_out, int out_size, void* d_ws, size_t ws_size,
                              hipStream_t stream) {
    const float* x  = (const float*)d_in[0];
    const float* uw = (const float*)d_in[1];
    const float* uh = (const float*)d_in[2];
    const float* ud = (const float*)d_in[3];
    const float* ul = (const float*)d_in[4];
    float* outp = (float*)d_out;

    const int B = in_sizes[0] / DD;   // 65536

    float4* parG = (float4*)d_ws;                                  // 256*16*16 = 64 KiB
    float*  bndG = (float*)((char*)d_ws + (size_t)DD * 16 * sizeof(float4)); // +15 KiB

    spline_setup<<<dim3((DD * KK + 255) / 256), dim3(256), 0, stream>>>(uw, uh, ud, ul, parG, bndG);
    spline_main<<<dim3(DD / DTILE, B / ROWS), dim3(256), 0, stream>>>(x, parG, bndG, outp, B);
}

// Round 4
// 124.526 us; speedup vs baseline: 1.0535x; 1.0535x over previous
//
#include <hip/hip_runtime.h>
#include <math.h>

// Problem constants (from setup_inputs): x[B,D] fp32, K=8 bins per column.
#define DD   256
#define KK   8
#define DTILE 128     // d-columns per block (2 per lane, float2-vectorized)
#define ROWS  128     // b-rows per block (32 per wave)

typedef float f32x2 __attribute__((ext_vector_type(2)));  // native clang vector:
// HIP's float2 is a class type that __builtin_nontemporal_store rejects (R1 compile fail).

// ---------------------------------------------------------------------------
// Setup kernel (UNCHANGED from verified 126us version): 8 lanes per column d.
// Width-8 shfl_xor softmax max/sum, width-8 shfl_up scan for knot cumsum,
// lane k emits bin k's two Mobius coefficient quads, composed in double.
// parG: float4[D*16]; bndG: float[D*15] interior boundaries s[1..15].
// ---------------------------------------------------------------------------
__global__ __launch_bounds__(256)
void spline_setup(const float* __restrict__ uw, const float* __restrict__ uh,
                  const float* __restrict__ ud, const float* __restrict__ ul,
                  float4* __restrict__ parG, float* __restrict__ bndG) {
    const int t = blockIdx.x * blockDim.x + threadIdx.x;   // 0..2047
    const int d = t >> 3;
    const int k = t & 7;
    if (d >= DD) return;

    const float uwv = uw[d * KK + k];
    const float uhv = uh[d * KK + k];
    const float ulv = ul[d * KK + k];

    float mw = uwv, mh = uhv;
    for (int off = 1; off < 8; off <<= 1) {
        mw = fmaxf(mw, __shfl_xor(mw, off, 8));
        mh = fmaxf(mh, __shfl_xor(mh, off, 8));
    }
    const float ew = expf(uwv - mw), eh = expf(uhv - mh);
    double sw = (double)ew, sh = (double)eh;
    for (int off = 1; off < 8; off <<= 1) {
        sw += __shfl_xor(sw, off, 8);
        sh += __shfl_xor(sh, off, 8);
    }
    const double wk = 1e-3 + (1.0 - 1e-3 * KK) * ((double)ew / sw);
    const double hk = 1e-3 + (1.0 - 1e-3 * KK) * ((double)eh / sh);

    double cw = wk, ch = hk;
    for (int off = 1; off < 8; off <<= 1) {
        const double aw = __shfl_up(cw, (unsigned)off, 8);
        const double ah = __shfl_up(ch, (unsigned)off, 8);
        if (k >= off) { cw += aw; ch += ah; }
    }

    const double kxlo = (k == 0) ? -3.0 : 6.0 * (cw - wk) - 3.0;
    const double kxhi = (k == 7) ?  3.0 : 6.0 * cw - 3.0;
    const double kylo = (k == 0) ? -3.0 : 6.0 * (ch - hk) - 3.0;
    const double kyhi = (k == 7) ?  3.0 : 6.0 * ch - 3.0;

    const double d0 = (k == 0) ? (1.0 - 1e-3)
                               : (1e-3 + (double)log1pf(expf(ud[d * (KK - 1) + k - 1])));
    const double d1 = (k == 7) ? (1.0 - 1e-3)
                               : (1e-3 + (double)log1pf(expf(ud[d * (KK - 1) + k])));
    const double l = 0.025 + 0.95 * (1.0 / (1.0 + (double)expf(-ulv)));

    const double wdt = kxhi - kxlo;
    const double hgt = kyhi - kylo;
    const double delta = hgt / wdt;
    const double wb = sqrt(d0 / d1);                       // wa = 1
    const double wc = (l * d0 + (1.0 - l) * wb * d1) / delta;
    const double ya = kylo, yb = kyhi;
    const double wcyc = wc * (((1.0 - l) * ya + l * wb * yb) / ((1.0 - l) + l * wb));
    const double wbyb = wb * yb;
    const double invw = 1.0 / wdt, icw = kxlo;

    {
        const double A = ya * l, P = wcyc - ya, C = l, Q = wc - 1.0;
        const double Bp = P * invw, Dp = Q * invw;
        parG[d * 16 + 2 * k] = make_float4((float)(A - Bp * icw), (float)Bp,
                                           (float)(C - Dp * icw), (float)Dp);
    }
    {
        const double A = wcyc - wbyb * l, P = wbyb - wcyc, C = wc - wb * l, Q = wb - wc;
        const double Bp = P * invw, Dp = Q * invw;
        parG[d * 16 + 2 * k + 1] = make_float4((float)(A - Bp * icw), (float)Bp,
                                               (float)(C - Dp * icw), (float)Dp);
    }
    if (k > 0) bndG[d * 15 + (2 * k - 1)] = (float)kxlo;
    bndG[d * 15 + (2 * k)] = (float)(kxlo + l * wdt);
}

// ---------------------------------------------------------------------------
// Per-element evaluator (math identical to verified version): branchless
// 4-level binary search over 15 register-resident boundaries, one rotated
// LDS float4 fetch, Mobius evaluate, identity outside [-3,3].
// ---------------------------------------------------------------------------
__device__ __forceinline__ float spline_eval(
    float xo,
    float b1, float b2, float b3, float b4, float b5, float b6, float b7, float b8,
    float b9, float b10, float b11, float b12, float b13, float b14, float b15,
    const float4* __restrict__ sp, int pbase, int rot) {
    const float xc = __builtin_amdgcn_fmed3f(xo, -3.0f, 3.0f);
    const bool c3 = xc >= b8;
    const float m2 = c3 ? b12 : b4;
    const bool c2 = xc >= m2;
    const float m1 = c3 ? (c2 ? b14 : b10) : (c2 ? b6 : b2);
    const bool c1 = xc >= m1;
    const float t01 = c1 ? b3  : b1;
    const float t23 = c1 ? b7  : b5;
    const float t45 = c1 ? b11 : b9;
    const float t67 = c1 ? b15 : b13;
    const float m0 = c3 ? (c2 ? t67 : t45) : (c2 ? t23 : t01);
    const bool c0 = xc >= m0;
    const int j = (c3 ? 8 : 0) + (c2 ? 4 : 0) + (c1 ? 2 : 0) + (c0 ? 1 : 0);

    const float4 p = sp[pbase + ((j + rot) & 15)];
    const float num = fmaf(p.y, xc, p.x);
    const float den = fmaf(p.w, xc, p.z);
    const float res = __fdividef(num, den);
    return (xo == xc) ? res : xo;   // outside [-3,3] (and NaN) -> identity
}

// ---------------------------------------------------------------------------
// Main kernel v3 (REVERT to R2, the best harness-verified version, 126.6us):
// float2-vectorized along D. Each lane owns 2 adjacent columns
// (d0 = dbase + 2*lane, d0+1); a wave's load covers 128 consecutive floats
// = 512B fully-coalesced, 8B/lane. R3's ping-pong pipeline variant measured
// 131.2us (slower): the timed window is dominated by ~123us of harness
// poison-fills at 82% HBM peak, and the duplicated pipeline body added real
// overhead to the small kernel slice. This version is the floor holder.
//
// LDS par layout [sub][grp][slot] with stride 17 float4 preserves the
// verified bank math: bank = 4*(lane+slot) mod 32, rotation rot = lane>>3
// spreads the 8-lane alias groups. sub=1 table starts at a 0 mod 32 bank
// offset (1088*4 % 32 == 0) -> identical bank behavior.
//
// Occupancy: LDS 34816B -> 4 blocks/CU; __launch_bounds__(256,4).
// Grid = (2, 512) = 1024 blocks = exactly 4/CU: one residency wave, no tail.
// ---------------------------------------------------------------------------
__global__ __launch_bounds__(256, 4)
void spline_main(const float* __restrict__ x, const float4* __restrict__ parG,
                 const float* __restrict__ bndG, float* __restrict__ out, int B) {
    __shared__ float4 s_par[2 * 64 * 17];   // 34816 B

    const int tid = threadIdx.x;
    const int dbase = blockIdx.x * DTILE;
    const int lane = tid & 63;
    const int w    = tid >> 6;
    const int d0   = dbase + lane * 2;

    const size_t rowbase = (size_t)(blockIdx.y * ROWS + w * 32) * DD + d0;
    const f32x2* __restrict__ xp = (const f32x2*)(x + rowbase);
    f32x2*       __restrict__ op = (f32x2*)(out + rowbase);
    const int RS = DD / 2;   // row stride in f32x2 units = 128

    // issue the first x-load quad before anything else (overlaps staging)
    f32x2 cur[4], nxt[4];
#pragma unroll
    for (int r = 0; r < 4; ++r) cur[r] = xp[(size_t)r * RS];

    // boundary loads for both owned columns (independent of LDS staging)
    const float* bpa = bndG + (size_t)d0 * 15;
    const float* bpb = bpa + 15;
    const float a1 = bpa[0],  a2 = bpa[1],  a3 = bpa[2],  a4 = bpa[3];
    const float a5 = bpa[4],  a6 = bpa[5],  a7 = bpa[6],  a8 = bpa[7];
    const float a9 = bpa[8],  a10 = bpa[9], a11 = bpa[10], a12 = bpa[11];
    const float a13 = bpa[12], a14 = bpa[13], a15 = bpa[14];
    const float c1 = bpb[0],  c2 = bpb[1],  c3 = bpb[2],  c4 = bpb[3];
    const float c5 = bpb[4],  c6 = bpb[5],  c7 = bpb[6],  c8 = bpb[7];
    const float c9 = bpb[8],  c10 = bpb[9], c11 = bpb[10], c12 = bpb[11];
    const float c13 = bpb[12], c14 = bpb[13], c15 = bpb[14];

    // stage par for the block's 128 columns; column c -> [c&1][c>>1][slot]
    for (int i = tid; i < DTILE * 16; i += 256) {
        const int col = i >> 4, v = i & 15;
        const int grp = col >> 1, sub = col & 1;
        s_par[(sub * 64 + grp) * 17 + ((v + (grp >> 3)) & 15)] =
            parG[(size_t)(dbase + col) * 16 + v];
    }
    __syncthreads();

    const int pb0 = lane * 17;           // sub=0 (even column d0)
    const int pb1 = (64 + lane) * 17;    // sub=1 (odd column d0+1)
    const int rot = lane >> 3;

#pragma unroll 1
    for (int g = 0; g < 8; ++g) {
        if (g < 7) {
#pragma unroll
            for (int r = 0; r < 4; ++r) nxt[r] = xp[(size_t)((g + 1) * 4 + r) * RS];
        }
#pragma unroll
        for (int r = 0; r < 4; ++r) {
            const f32x2 v = cur[r];
            f32x2 o;
            o.x = spline_eval(v.x, a1, a2, a3, a4, a5, a6, a7, a8,
                              a9, a10, a11, a12, a13, a14, a15, s_par, pb0, rot);
            o.y = spline_eval(v.y, c1, c2, c3, c4, c5, c6, c7, c8,
                              c9, c10, c11, c12, c13, c14, c15, s_par, pb1, rot);
            __builtin_nontemporal_store(o, &op[(size_t)(g * 4 + r) * RS]);
        }
#pragma unroll
        for (int r = 0; r < 4; ++r) cur[r] = nxt[r];
    }
}

extern "C" void kernel_launch(void* const* d_in, const int* in_sizes, int n_in,
                              void* d_out, int out_size, void* d_ws, size_t ws_size,
                              hipStream_t stream) {
    const float* x  = (const float*)d_in[0];
    const float* uw = (const float*)d_in[1];
    const float* uh = (const float*)d_in[2];
    const float* ud = (const float*)d_in[3];
    const float* ul = (const float*)d_in[4];
    float* outp = (float*)d_out;

    const int B = in_sizes[0] / DD;   // 65536

    float4* parG = (float4*)d_ws;                                  // 256*16*16 = 64 KiB
    float*  bndG = (float*)((char*)d_ws + (size_t)DD * 16 * sizeof(float4)); // +15 KiB

    spline_setup<<<dim3((DD * KK + 255) / 256), dim3(256), 0, stream>>>(uw, uh, ud, ul, parG, bndG);
    spline_main<<<dim3(DD / DTILE, B / ROWS), dim3(256), 0, stream>>>(x, parG, bndG, outp, B);
}